// Round 2
// baseline (401.760 us; speedup 1.0000x reference)
//
#include <hip/hip_runtime.h>
#include <hip/hip_bf16.h>

typedef __attribute__((ext_vector_type(8))) short bf16x8;
typedef __attribute__((ext_vector_type(4))) float f32x4;
typedef __attribute__((ext_vector_type(4))) int i32x4;
typedef __attribute__((ext_vector_type(4))) unsigned short u16x4;
typedef __attribute__((ext_vector_type(4))) float fl4;

#define NEGV -1e9f

__device__ __forceinline__ f32x4 mfma16(bf16x8 a, bf16x8 b, f32x4 c) {
    return __builtin_amdgcn_mfma_f32_16x16x32_bf16(a, b, c, 0, 0, 0);
}

__device__ __forceinline__ unsigned short f2b(float f) {
    unsigned u = __float_as_uint(f);
    unsigned r = (u + 0x7FFF + ((u >> 16) & 1)) >> 16;
    return (unsigned short)r;
}

// -------- dtype detect: flag=1 if att_in is raw float32 data ----------------
__global__ void k_detect(const unsigned short* __restrict__ src, int* __restrict__ flag) {
    __shared__ int sh[256];
    int tid = threadIdx.x;
    int h = 0;
    for (int i = tid; i < 16384; i += 256) {
        unsigned e = (src[i] >> 7) & 0xFF;
        if (e == 0xFF) h = 1;   // NaN/Inf bit pattern when viewed as bf16
    }
    sh[tid] = h;
    __syncthreads();
    if (tid == 0) {
        int any = 0;
        for (int i = 0; i < 256; ++i) any |= sh[i];
        flag[0] = any;
    }
}

// -------- zero d_out (size depends on output dtype) -------------------------
__global__ void k_zero(char* __restrict__ out, long long out_elems, const int* __restrict__ flag) {
    long long bytes = flag[0] ? out_elems * 4 : out_elems * 2;
    long long i = ((long long)blockIdx.x * 256 + threadIdx.x) * 16;
    if (i < bytes) *(i32x4*)(out + i) = (i32x4){0, 0, 0, 0};
}

// -------- offsets: exclusive cumsum of agents[64], offs[64]=total -----------
__global__ void k_offsets(const int* __restrict__ agents, int* __restrict__ offs) {
    __shared__ int sa[64];
    int t = threadIdx.x;
    sa[t] = agents[t];
    __syncthreads();
    int ex = 0;
    for (int i = 0; i < 64; ++i) { int v = sa[i]; if (i < t) ex += v; }
    offs[t] = ex;
    if (t == 63) offs[64] = ex + sa[63];
}

// -------- cast tensor to canonical bf16 (n % 4 == 0) ------------------------
__global__ void k_cast(const void* __restrict__ src, unsigned short* __restrict__ dst,
                       int n, const int* __restrict__ flag) {
    int i = (blockIdx.x * 256 + threadIdx.x) * 4;
    if (i >= n) return;
    u16x4 o;
    if (flag[0]) {
        fl4 v = *(const fl4*)((const float*)src + i);
        o[0] = f2b(v[0]); o[1] = f2b(v[1]); o[2] = f2b(v[2]); o[3] = f2b(v[3]);
    } else {
        o = *(const u16x4*)((const unsigned short*)src + i);
    }
    *(u16x4*)(dst + i) = o;
}

// -------- cast bias to canonical f32 ---------------------------------------
__global__ void k_castb(const void* __restrict__ src, float* __restrict__ dst,
                        int n, const int* __restrict__ flag) {
    int i = blockIdx.x * 256 + threadIdx.x;
    if (i >= n) return;
    dst[i] = flag[0] ? ((const float*)src)[i]
                     : __bfloat162float(((const __hip_bfloat16*)src)[i]);
}

// -------- QKV projection: qk[total][1024], vT[b][h][64][256] ----------------
__global__ __launch_bounds__(256) void k_qkv(
    const __hip_bfloat16* __restrict__ A,    // [total][512] bf16 canonical
    const __hip_bfloat16* __restrict__ W,    // [1536][512]
    const float* __restrict__ bias,          // [1536] f32 canonical
    const int* __restrict__ offs,            // [65]
    __hip_bfloat16* __restrict__ qk,         // [total][1024]
    __hip_bfloat16* __restrict__ vT,         // [64*8*64][256]
    int total)
{
    __shared__ int s_off[65];
    int tid = threadIdx.x;
    if (tid < 65) s_off[tid] = offs[tid];
    __syncthreads();
    int wave = tid >> 6, lane = tid & 63;
    int quad = lane >> 4, c = lane & 15;
    int n0 = blockIdx.x * 64;
    int m0 = blockIdx.y * 64 + wave * 16;
    int ar = m0 + c; if (ar > total - 1) ar = total - 1;
    const __hip_bfloat16* Ap  = A + (size_t)ar * 512 + quad * 8;
    const __hip_bfloat16* Wp0 = W + (size_t)(n0 +  0 + c) * 512 + quad * 8;
    const __hip_bfloat16* Wp1 = W + (size_t)(n0 + 16 + c) * 512 + quad * 8;
    const __hip_bfloat16* Wp2 = W + (size_t)(n0 + 32 + c) * 512 + quad * 8;
    const __hip_bfloat16* Wp3 = W + (size_t)(n0 + 48 + c) * 512 + quad * 8;
    f32x4 z = {0.f, 0.f, 0.f, 0.f};
    f32x4 acc[4] = {z, z, z, z};
#pragma unroll
    for (int k = 0; k < 512; k += 32) {
        bf16x8 a = *(const bf16x8*)(Ap + k);
        acc[0] = mfma16(a, *(const bf16x8*)(Wp0 + k), acc[0]);
        acc[1] = mfma16(a, *(const bf16x8*)(Wp1 + k), acc[1]);
        acc[2] = mfma16(a, *(const bf16x8*)(Wp2 + k), acc[2]);
        acc[3] = mfma16(a, *(const bf16x8*)(Wp3 + k), acc[3]);
    }
    bool vregion = (n0 >= 1024);
    int vb[4], vs[4];
    if (vregion) {
#pragma unroll
        for (int r = 0; r < 4; ++r) {
            int m = m0 + quad * 4 + r; if (m > total - 1) m = total - 1;
            int lo = 0, hi = 63;
            while (lo < hi) {
                int mid = (lo + hi + 1) >> 1;
                if (s_off[mid] <= m) lo = mid; else hi = mid - 1;
            }
            vb[r] = lo; vs[r] = m - s_off[lo];
        }
    }
#pragma unroll
    for (int t = 0; t < 4; ++t) {
        int col = n0 + t * 16 + c;
        float bv = bias[col];
#pragma unroll
        for (int r = 0; r < 4; ++r) {
            int m = m0 + quad * 4 + r;
            if (m < total) {
                __hip_bfloat16 val = __float2bfloat16(acc[t][r] + bv);
                if (!vregion) {
                    qk[(size_t)m * 1024 + col] = val;
                } else {
                    int vc = col - 1024;
                    vT[((size_t)(vb[r] * 8 + (vc >> 6)) * 64 + (vc & 63)) * 256 + vs[r]] = val;
                }
            }
        }
    }
}

// -------- attention: one workgroup per (b,h); ctx written into q-half of qk -
__global__ __launch_bounds__(256) void k_attn(
    __hip_bfloat16* __restrict__ qk,         // [total][1024]; cols 0..511 become ctx
    const __hip_bfloat16* __restrict__ vT,   // [64*8*64][256]
    const int* __restrict__ agents,
    const int* __restrict__ offs)
{
    __shared__ __hip_bfloat16 P[4][16][264];
    __shared__ float invs[4][16];
    int bh = blockIdx.x;
    int b = bh >> 3, h = bh & 7;
    int n = agents[b];
    int off = offs[b];
    int tid = threadIdx.x;
    int wave = tid >> 6, lane = tid & 63, quad = lane >> 4, c = lane & 15;
    int qtiles = (n + 15) >> 4;
    int iters = (qtiles + 3) >> 2;
    const __hip_bfloat16* vbase = vT + (size_t)bh * 64 * 256;

    for (int it = 0; it < iters; ++it) {
        int qt = it * 4 + wave;
        bool active = qt < qtiles;
        int q0 = qt * 16;
        if (active) {
            int qr = q0 + c; if (qr > n - 1) qr = n - 1;
            const __hip_bfloat16* qp = qk + (size_t)(off + qr) * 1024 + h * 64 + quad * 8;
            bf16x8 aq0 = *(const bf16x8*)qp;
            bf16x8 aq1 = *(const bf16x8*)(qp + 32);
            f32x4 S[16];
#pragma unroll
            for (int kt = 0; kt < 16; ++kt) {
                int kr = kt * 16 + c; if (kr > n - 1) kr = n - 1;
                const __hip_bfloat16* kp = qk + (size_t)(off + kr) * 1024 + 512 + h * 64 + quad * 8;
                f32x4 zz = {0.f, 0.f, 0.f, 0.f};
                zz = mfma16(aq0, *(const bf16x8*)kp, zz);
                zz = mfma16(aq1, *(const bf16x8*)(kp + 32), zz);
                S[kt] = zz;
            }
            float mr[4] = {-1e30f, -1e30f, -1e30f, -1e30f};
#pragma unroll
            for (int kt = 0; kt < 16; ++kt) {
                bool bad = (kt * 16 + c) >= n;
#pragma unroll
                for (int r = 0; r < 4; ++r) {
                    float s = bad ? NEGV : S[kt][r];
                    S[kt][r] = s;
                    mr[r] = fmaxf(mr[r], s);
                }
            }
#pragma unroll
            for (int r = 0; r < 4; ++r) {
                float v = mr[r];
                v = fmaxf(v, __shfl_xor(v, 1));
                v = fmaxf(v, __shfl_xor(v, 2));
                v = fmaxf(v, __shfl_xor(v, 4));
                v = fmaxf(v, __shfl_xor(v, 8));
                mr[r] = v;
            }
            float sm[4] = {0.f, 0.f, 0.f, 0.f};
#pragma unroll
            for (int kt = 0; kt < 16; ++kt) {
#pragma unroll
                for (int r = 0; r < 4; ++r) {
                    float p = __expf((S[kt][r] - mr[r]) * 0.125f);
                    sm[r] += p;
                    P[wave][quad * 4 + r][kt * 16 + c] = __float2bfloat16(p);
                }
            }
#pragma unroll
            for (int r = 0; r < 4; ++r) {
                float v = sm[r];
                v += __shfl_xor(v, 1);
                v += __shfl_xor(v, 2);
                v += __shfl_xor(v, 4);
                v += __shfl_xor(v, 8);
                if (c == 0) invs[wave][quad * 4 + r] = 1.0f / v;
            }
        }
        __syncthreads();
        if (active) {
            f32x4 z = {0.f, 0.f, 0.f, 0.f};
            f32x4 O[4] = {z, z, z, z};
#pragma unroll
            for (int st = 0; st < 8; ++st) {
                bf16x8 ap = *(const bf16x8*)&P[wave][c][st * 32 + quad * 8];
#pragma unroll
                for (int dt = 0; dt < 4; ++dt) {
                    const __hip_bfloat16* vp = vbase + (size_t)(c + 16 * dt) * 256 + st * 32 + quad * 8;
                    O[dt] = mfma16(ap, *(const bf16x8*)vp, O[dt]);
                }
            }
#pragma unroll
            for (int r = 0; r < 4; ++r) {
                int q = quad * 4 + r;
                if (q0 + q < n) {
                    float iv = invs[wave][q];
                    size_t row = (size_t)(off + q0 + q) * 1024 + h * 64;
#pragma unroll
                    for (int dt = 0; dt < 4; ++dt)
                        qk[row + 16 * dt + c] = __float2bfloat16(O[dt][r] * iv);
                }
            }
        }
        __syncthreads();
    }
}

// -------- output projection into padded, zeroed d_out -----------------------
__global__ __launch_bounds__(256) void k_out(
    const __hip_bfloat16* __restrict__ A,    // ctx in qk buffer, stride 1024
    const __hip_bfloat16* __restrict__ W,    // [512][512]
    const float* __restrict__ bias,          // [512] f32 canonical
    const int* __restrict__ offs,            // [65]
    void* __restrict__ out,                  // [64][254][512] f32 or bf16
    const int* __restrict__ flag,
    int total)
{
    __shared__ int s_off[65];
    int tid = threadIdx.x;
    if (tid < 65) s_off[tid] = offs[tid];
    __syncthreads();
    int f32m = flag[0];
    int wave = tid >> 6, lane = tid & 63;
    int quad = lane >> 4, c = lane & 15;
    int n0 = blockIdx.x * 64;
    int m0 = blockIdx.y * 64 + wave * 16;
    int ar = m0 + c; if (ar > total - 1) ar = total - 1;
    const __hip_bfloat16* Ap  = A + (size_t)ar * 1024 + quad * 8;
    const __hip_bfloat16* Wp0 = W + (size_t)(n0 +  0 + c) * 512 + quad * 8;
    const __hip_bfloat16* Wp1 = W + (size_t)(n0 + 16 + c) * 512 + quad * 8;
    const __hip_bfloat16* Wp2 = W + (size_t)(n0 + 32 + c) * 512 + quad * 8;
    const __hip_bfloat16* Wp3 = W + (size_t)(n0 + 48 + c) * 512 + quad * 8;
    f32x4 z = {0.f, 0.f, 0.f, 0.f};
    f32x4 acc[4] = {z, z, z, z};
#pragma unroll
    for (int k = 0; k < 512; k += 32) {
        bf16x8 a = *(const bf16x8*)(Ap + k);
        acc[0] = mfma16(a, *(const bf16x8*)(Wp0 + k), acc[0]);
        acc[1] = mfma16(a, *(const bf16x8*)(Wp1 + k), acc[1]);
        acc[2] = mfma16(a, *(const bf16x8*)(Wp2 + k), acc[2]);
        acc[3] = mfma16(a, *(const bf16x8*)(Wp3 + k), acc[3]);
    }
    int ob[4], os_[4];
#pragma unroll
    for (int r = 0; r < 4; ++r) {
        int m = m0 + quad * 4 + r; if (m > total - 1) m = total - 1;
        int lo = 0, hi = 63;
        while (lo < hi) {
            int mid = (lo + hi + 1) >> 1;
            if (s_off[mid] <= m) lo = mid; else hi = mid - 1;
        }
        ob[r] = lo; os_[r] = m - s_off[lo];
    }
#pragma unroll
    for (int t = 0; t < 4; ++t) {
        int col = n0 + t * 16 + c;
        float bv = bias[col];
#pragma unroll
        for (int r = 0; r < 4; ++r) {
            int m = m0 + quad * 4 + r;
            if (m < total) {
                size_t idx = ((size_t)(ob[r] * 254 + os_[r])) * 512 + col;
                float v = acc[t][r] + bv;
                if (f32m) ((float*)out)[idx] = v;
                else      ((__hip_bfloat16*)out)[idx] = __float2bfloat16(v);
            }
        }
    }
}

extern "C" void kernel_launch(void* const* d_in, const int* in_sizes, int n_in,
                              void* d_out, int out_size, void* d_ws, size_t ws_size,
                              hipStream_t stream) {
    const void* att_in = d_in[0];
    const void* w_in   = d_in[1];
    const void* b_in   = d_in[2];
    const void* w_out  = d_in[3];
    const void* b_out  = d_in[4];
    const int* agents  = (const int*)d_in[5];
    int total = in_sizes[0] / 512;

    char* p = (char*)d_ws;
    int* flag  = (int*)p;                 p += 256;
    int* offs  = (int*)p;                 p += 512;
    float* bfi = (float*)p;               p += 1536 * 4;
    float* bfo = (float*)p;               p += 512 * 4;
    __hip_bfloat16* WinBf  = (__hip_bfloat16*)p;  p += (size_t)1536 * 512 * 2;
    __hip_bfloat16* WoutBf = (__hip_bfloat16*)p;  p += (size_t)512 * 512 * 2;
    __hip_bfloat16* Abf    = (__hip_bfloat16*)p;  p += (size_t)total * 512 * 2;
    __hip_bfloat16* qk     = (__hip_bfloat16*)p;  p += (size_t)total * 1024 * 2;
    __hip_bfloat16* vT     = (__hip_bfloat16*)p;  p += (size_t)64 * 8 * 64 * 256 * 2;

    int nA = total * 512, nWi = 1536 * 512, nWo = 512 * 512;

    k_detect<<<1, 256, 0, stream>>>((const unsigned short*)att_in, flag);
    long long zblocks = ((long long)out_size * 4 / 16 + 255) / 256;
    k_zero<<<(int)zblocks, 256, 0, stream>>>((char*)d_out, out_size, flag);
    k_offsets<<<1, 64, 0, stream>>>(agents, offs);
    k_cast<<<(nA / 4 + 255) / 256, 256, 0, stream>>>(att_in, (unsigned short*)Abf, nA, flag);
    k_cast<<<(nWi / 4 + 255) / 256, 256, 0, stream>>>(w_in, (unsigned short*)WinBf, nWi, flag);
    k_cast<<<(nWo / 4 + 255) / 256, 256, 0, stream>>>(w_out, (unsigned short*)WoutBf, nWo, flag);
    k_castb<<<(1536 + 255) / 256, 256, 0, stream>>>(b_in, bfi, 1536, flag);
    k_castb<<<(512 + 255) / 256, 256, 0, stream>>>(b_out, bfo, 512, flag);

    int MT = (total + 63) / 64;
    k_qkv<<<dim3(24, MT), 256, 0, stream>>>(Abf, WinBf, bfi, offs, qk, vT, total);
    k_attn<<<512, 256, 0, stream>>>(qk, vT, agents, offs);
    k_out<<<dim3(8, MT), 256, 0, stream>>>(qk, WoutBf, bfo, offs, d_out, flag, total);
}

// Round 3
// 246.916 us; speedup vs baseline: 1.6271x; 1.6271x over previous
//
#include <hip/hip_runtime.h>
#include <hip/hip_bf16.h>

typedef __attribute__((ext_vector_type(8))) short bf16x8;
typedef __attribute__((ext_vector_type(4))) float f32x4;
typedef __attribute__((ext_vector_type(4))) int i32x4;
typedef __attribute__((ext_vector_type(4))) unsigned short u16x4;
typedef __attribute__((ext_vector_type(4))) float fl4;

#define NEGV -1e9f

__device__ __forceinline__ f32x4 mfma16(bf16x8 a, bf16x8 b, f32x4 c) {
    return __builtin_amdgcn_mfma_f32_16x16x32_bf16(a, b, c, 0, 0, 0);
}

__device__ __forceinline__ unsigned short f2b(float f) {
    unsigned u = __float_as_uint(f);
    unsigned r = (u + 0x7FFF + ((u >> 16) & 1)) >> 16;
    return (unsigned short)r;
}

// async global->LDS, 16B per lane; lds base must be wave-uniform (HW adds lane*16)
__device__ __forceinline__ void gld_lds16(const __hip_bfloat16* g, __hip_bfloat16* l) {
    __builtin_amdgcn_global_load_lds(
        (const __attribute__((address_space(1))) void*)g,
        (__attribute__((address_space(3))) void*)l,
        16, 0, 0);
}

// -------- dtype detect: flag=1 if att_in is raw float32 data ----------------
__global__ void k_detect(const unsigned short* __restrict__ src, int* __restrict__ flag) {
    __shared__ int sh[256];
    int tid = threadIdx.x;
    int h = 0;
    for (int i = tid; i < 16384; i += 256) {
        unsigned e = (src[i] >> 7) & 0xFF;
        if (e == 0xFF) h = 1;
    }
    sh[tid] = h;
    __syncthreads();
    if (tid == 0) {
        int any = 0;
        for (int i = 0; i < 256; ++i) any |= sh[i];
        flag[0] = any;
    }
}

// -------- zero d_out (size depends on output dtype) -------------------------
__global__ void k_zero(char* __restrict__ out, long long out_elems, const int* __restrict__ flag) {
    long long bytes = flag[0] ? out_elems * 4 : out_elems * 2;
    long long i = ((long long)blockIdx.x * 256 + threadIdx.x) * 16;
    if (i < bytes) *(i32x4*)(out + i) = (i32x4){0, 0, 0, 0};
}

// -------- offsets: exclusive cumsum of agents[64], offs[64]=total -----------
__global__ void k_offsets(const int* __restrict__ agents, int* __restrict__ offs) {
    __shared__ int sa[64];
    int t = threadIdx.x;
    sa[t] = agents[t];
    __syncthreads();
    int ex = 0;
    for (int i = 0; i < 64; ++i) { int v = sa[i]; if (i < t) ex += v; }
    offs[t] = ex;
    if (t == 63) offs[64] = ex + sa[63];
}

// -------- cast tensor to canonical bf16 (n % 4 == 0) ------------------------
__global__ void k_cast(const void* __restrict__ src, unsigned short* __restrict__ dst,
                       int n, const int* __restrict__ flag) {
    int i = (blockIdx.x * 256 + threadIdx.x) * 4;
    if (i >= n) return;
    u16x4 o;
    if (flag[0]) {
        fl4 v = *(const fl4*)((const float*)src + i);
        o[0] = f2b(v[0]); o[1] = f2b(v[1]); o[2] = f2b(v[2]); o[3] = f2b(v[3]);
    } else {
        o = *(const u16x4*)((const unsigned short*)src + i);
    }
    *(u16x4*)(dst + i) = o;
}

// -------- cast bias to canonical f32 ---------------------------------------
__global__ void k_castb(const void* __restrict__ src, float* __restrict__ dst,
                        int n, const int* __restrict__ flag) {
    int i = blockIdx.x * 256 + threadIdx.x;
    if (i >= n) return;
    dst[i] = flag[0] ? ((const float*)src)[i]
                     : __bfloat162float(((const __hip_bfloat16*)src)[i]);
}

// -------- m97-style 128x128x512 GEMM core (A row-major LDA, W [N][512]) -----
// acc[i][j]: m = m0 + wr*64 + i*16 + quad*4 + reg ; col = n0 + wc*64 + j*16 + c
template<int LDA>
__device__ __forceinline__ void gemm_core(
    const __hip_bfloat16* __restrict__ A,
    const __hip_bfloat16* __restrict__ W,
    int m0, int n0, int total,
    __hip_bfloat16* As, __hip_bfloat16* Ws,
    f32x4 acc[4][4], int tid)
{
    int lane = tid & 63, quad = lane >> 4, c = lane & 15;
    int wave = tid >> 6;
    int wr = wave >> 1, wc = wave & 1;

    int chunk0 = tid;          // [0,256)
    int chunk1 = 256 + tid;    // [256,512)
    int ar0 = m0 + (chunk0 >> 2); if (ar0 > total - 1) ar0 = total - 1;
    int ar1 = m0 + (chunk1 >> 2); if (ar1 > total - 1) ar1 = total - 1;
    const __hip_bfloat16* gA0 = A + (size_t)ar0 * LDA + (chunk0 & 3) * 8;
    const __hip_bfloat16* gA1 = A + (size_t)ar1 * LDA + (chunk1 & 3) * 8;
    const __hip_bfloat16* gW0 = W + (size_t)(n0 + (chunk0 >> 2)) * 512 + (chunk0 & 3) * 8;
    const __hip_bfloat16* gW1 = W + (size_t)(n0 + (chunk1 >> 2)) * 512 + (chunk1 & 3) * 8;
    __hip_bfloat16* lA0 = As + (size_t)(wave * 64) * 8;          // wave-uniform
    __hip_bfloat16* lA1 = As + (size_t)(256 + wave * 64) * 8;
    __hip_bfloat16* lW0 = Ws + (size_t)(wave * 64) * 8;
    __hip_bfloat16* lW1 = Ws + (size_t)(256 + wave * 64) * 8;

    for (int k0 = 0; k0 < 512; k0 += 32) {
        if (k0) __syncthreads();
        gld_lds16(gA0 + k0, lA0);
        gld_lds16(gA1 + k0, lA1);
        gld_lds16(gW0 + k0, lW0);
        gld_lds16(gW1 + k0, lW1);
        __syncthreads();
        bf16x8 af[4], wf[4];
#pragma unroll
        for (int t = 0; t < 4; ++t) {
            af[t] = *(const bf16x8*)(As + (size_t)(wr * 64 + t * 16 + c) * 32 + quad * 8);
            wf[t] = *(const bf16x8*)(Ws + (size_t)(wc * 64 + t * 16 + c) * 32 + quad * 8);
        }
#pragma unroll
        for (int i = 0; i < 4; ++i)
#pragma unroll
            for (int j = 0; j < 4; ++j)
                acc[i][j] = mfma16(af[i], wf[j], acc[i][j]);
    }
}

// -------- QKV projection: qk[total][1024], vT[b][h][64][256] ----------------
__global__ __launch_bounds__(256) void k_qkv(
    const __hip_bfloat16* __restrict__ A,    // [total][512]
    const __hip_bfloat16* __restrict__ W,    // [1536][512]
    const float* __restrict__ bias,          // [1536]
    const int* __restrict__ offs,            // [65]
    __hip_bfloat16* __restrict__ qk,         // [total][1024]
    __hip_bfloat16* __restrict__ vT,         // [64*8*64][256]
    int total)
{
    __shared__ __hip_bfloat16 As[128 * 32];
    __shared__ __hip_bfloat16 Ws[128 * 32];
    __shared__ int s_off[65];
    int tid = threadIdx.x;
    if (tid < 65) s_off[tid] = offs[tid];
    int n0 = blockIdx.x * 128;
    int m0 = blockIdx.y * 128;
    f32x4 z = {0.f, 0.f, 0.f, 0.f};
    f32x4 acc[4][4] = {{z,z,z,z},{z,z,z,z},{z,z,z,z},{z,z,z,z}};
    gemm_core<512>(A, W, m0, n0, total, As, Ws, acc, tid);

    int lane = tid & 63, quad = lane >> 4, c = lane & 15;
    int wave = tid >> 6, wr = wave >> 1, wc = wave & 1;
    bool vregion = (n0 >= 1024);
    float bv[4];
#pragma unroll
    for (int j = 0; j < 4; ++j) bv[j] = bias[n0 + wc * 64 + j * 16 + c];
#pragma unroll
    for (int i = 0; i < 4; ++i) {
#pragma unroll
        for (int r = 0; r < 4; ++r) {
            int m = m0 + wr * 64 + i * 16 + quad * 4 + r;
            if (m >= total) continue;
            if (!vregion) {
                size_t row = (size_t)m * 1024;
#pragma unroll
                for (int j = 0; j < 4; ++j) {
                    int col = n0 + wc * 64 + j * 16 + c;
                    qk[row + col] = __float2bfloat16(acc[i][j][r] + bv[j]);
                }
            } else {
                int lo = 0, hi = 63;
                while (lo < hi) {
                    int mid = (lo + hi + 1) >> 1;
                    if (s_off[mid] <= m) lo = mid; else hi = mid - 1;
                }
                int vs = m - s_off[lo];
#pragma unroll
                for (int j = 0; j < 4; ++j) {
                    int vc = n0 - 1024 + wc * 64 + j * 16 + c;
                    vT[((size_t)(lo * 8 + (vc >> 6)) * 64 + (vc & 63)) * 256 + vs] =
                        __float2bfloat16(acc[i][j][r] + bv[j]);
                }
            }
        }
    }
}

// -------- attention: one workgroup per (b,h); ctx written into q-half of qk -
__global__ __launch_bounds__(256) void k_attn(
    __hip_bfloat16* __restrict__ qk,         // [total][1024]; cols 0..511 become ctx
    const __hip_bfloat16* __restrict__ vT,   // [64*8*64][256]
    const int* __restrict__ agents,
    const int* __restrict__ offs)
{
    __shared__ __hip_bfloat16 P[4][16][264];
    __shared__ float invs[4][16];
    int bh = blockIdx.x;
    int b = bh >> 3, h = bh & 7;
    int n = agents[b];
    int off = offs[b];
    int tid = threadIdx.x;
    int wave = tid >> 6, lane = tid & 63, quad = lane >> 4, c = lane & 15;
    int qtiles = (n + 15) >> 4;
    int iters = (qtiles + 3) >> 2;
    const __hip_bfloat16* vbase = vT + (size_t)bh * 64 * 256;

    for (int it = 0; it < iters; ++it) {
        int qt = it * 4 + wave;
        bool active = qt < qtiles;
        int q0 = qt * 16;
        if (active) {
            int qr = q0 + c; if (qr > n - 1) qr = n - 1;
            const __hip_bfloat16* qp = qk + (size_t)(off + qr) * 1024 + h * 64 + quad * 8;
            bf16x8 aq0 = *(const bf16x8*)qp;
            bf16x8 aq1 = *(const bf16x8*)(qp + 32);
            f32x4 S[16];
#pragma unroll
            for (int kt = 0; kt < 16; ++kt) {
                int kr = kt * 16 + c; if (kr > n - 1) kr = n - 1;
                const __hip_bfloat16* kp = qk + (size_t)(off + kr) * 1024 + 512 + h * 64 + quad * 8;
                f32x4 zz = {0.f, 0.f, 0.f, 0.f};
                zz = mfma16(aq0, *(const bf16x8*)kp, zz);
                zz = mfma16(aq1, *(const bf16x8*)(kp + 32), zz);
                S[kt] = zz;
            }
            float mr[4] = {-1e30f, -1e30f, -1e30f, -1e30f};
#pragma unroll
            for (int kt = 0; kt < 16; ++kt) {
                bool bad = (kt * 16 + c) >= n;
#pragma unroll
                for (int r = 0; r < 4; ++r) {
                    float s = bad ? NEGV : S[kt][r];
                    S[kt][r] = s;
                    mr[r] = fmaxf(mr[r], s);
                }
            }
#pragma unroll
            for (int r = 0; r < 4; ++r) {
                float v = mr[r];
                v = fmaxf(v, __shfl_xor(v, 1));
                v = fmaxf(v, __shfl_xor(v, 2));
                v = fmaxf(v, __shfl_xor(v, 4));
                v = fmaxf(v, __shfl_xor(v, 8));
                mr[r] = v;
            }
            float sm[4] = {0.f, 0.f, 0.f, 0.f};
#pragma unroll
            for (int kt = 0; kt < 16; ++kt) {
#pragma unroll
                for (int r = 0; r < 4; ++r) {
                    float p = __expf((S[kt][r] - mr[r]) * 0.125f);
                    sm[r] += p;
                    P[wave][quad * 4 + r][kt * 16 + c] = __float2bfloat16(p);
                }
            }
#pragma unroll
            for (int r = 0; r < 4; ++r) {
                float v = sm[r];
                v += __shfl_xor(v, 1);
                v += __shfl_xor(v, 2);
                v += __shfl_xor(v, 4);
                v += __shfl_xor(v, 8);
                if (c == 0) invs[wave][quad * 4 + r] = 1.0f / v;
            }
        }
        __syncthreads();
        if (active) {
            f32x4 z = {0.f, 0.f, 0.f, 0.f};
            f32x4 O[4] = {z, z, z, z};
#pragma unroll
            for (int st = 0; st < 8; ++st) {
                bf16x8 ap = *(const bf16x8*)&P[wave][c][st * 32 + quad * 8];
#pragma unroll
                for (int dt = 0; dt < 4; ++dt) {
                    const __hip_bfloat16* vp = vbase + (size_t)(c + 16 * dt) * 256 + st * 32 + quad * 8;
                    O[dt] = mfma16(ap, *(const bf16x8*)vp, O[dt]);
                }
            }
#pragma unroll
            for (int r = 0; r < 4; ++r) {
                int q = quad * 4 + r;
                if (q0 + q < n) {
                    float iv = invs[wave][q];
                    size_t row = (size_t)(off + q0 + q) * 1024 + h * 64;
#pragma unroll
                    for (int dt = 0; dt < 4; ++dt)
                        qk[row + 16 * dt + c] = __float2bfloat16(O[dt][r] * iv);
                }
            }
        }
        __syncthreads();
    }
}

// -------- output projection into padded, zeroed d_out -----------------------
__global__ __launch_bounds__(256) void k_out(
    const __hip_bfloat16* __restrict__ A,    // ctx in qk buffer, stride 1024
    const __hip_bfloat16* __restrict__ W,    // [512][512]
    const float* __restrict__ bias,          // [512]
    const int* __restrict__ offs,            // [65]
    void* __restrict__ out,                  // [64][254][512] f32 or bf16
    const int* __restrict__ flag,
    int total)
{
    __shared__ __hip_bfloat16 As[128 * 32];
    __shared__ __hip_bfloat16 Ws[128 * 32];
    __shared__ int s_off[65];
    int tid = threadIdx.x;
    if (tid < 65) s_off[tid] = offs[tid];
    int n0 = blockIdx.x * 128;
    int m0 = blockIdx.y * 128;
    f32x4 z = {0.f, 0.f, 0.f, 0.f};
    f32x4 acc[4][4] = {{z,z,z,z},{z,z,z,z},{z,z,z,z},{z,z,z,z}};
    gemm_core<1024>(A, W, m0, n0, total, As, Ws, acc, tid);

    int f32m = flag[0];
    int lane = tid & 63, quad = lane >> 4, c = lane & 15;
    int wave = tid >> 6, wr = wave >> 1, wc = wave & 1;
    float bv[4];
#pragma unroll
    for (int j = 0; j < 4; ++j) bv[j] = bias[n0 + wc * 64 + j * 16 + c];
#pragma unroll
    for (int i = 0; i < 4; ++i) {
#pragma unroll
        for (int r = 0; r < 4; ++r) {
            int m = m0 + wr * 64 + i * 16 + quad * 4 + r;
            if (m >= total) continue;
            int lo = 0, hi = 63;
            while (lo < hi) {
                int mid = (lo + hi + 1) >> 1;
                if (s_off[mid] <= m) lo = mid; else hi = mid - 1;
            }
            int os_ = m - s_off[lo];
            size_t rowb = ((size_t)(lo * 254 + os_)) * 512;
#pragma unroll
            for (int j = 0; j < 4; ++j) {
                int col = n0 + wc * 64 + j * 16 + c;
                float v = acc[i][j][r] + bv[j];
                if (f32m) ((float*)out)[rowb + col] = v;
                else      ((__hip_bfloat16*)out)[rowb + col] = __float2bfloat16(v);
            }
        }
    }
}

extern "C" void kernel_launch(void* const* d_in, const int* in_sizes, int n_in,
                              void* d_out, int out_size, void* d_ws, size_t ws_size,
                              hipStream_t stream) {
    const void* att_in = d_in[0];
    const void* w_in   = d_in[1];
    const void* b_in   = d_in[2];
    const void* w_out  = d_in[3];
    const void* b_out  = d_in[4];
    const int* agents  = (const int*)d_in[5];
    int total = in_sizes[0] / 512;

    char* p = (char*)d_ws;
    int* flag  = (int*)p;                 p += 256;
    int* offs  = (int*)p;                 p += 512;
    float* bfi = (float*)p;               p += 1536 * 4;
    float* bfo = (float*)p;               p += 512 * 4;
    __hip_bfloat16* WinBf  = (__hip_bfloat16*)p;  p += (size_t)1536 * 512 * 2;
    __hip_bfloat16* WoutBf = (__hip_bfloat16*)p;  p += (size_t)512 * 512 * 2;
    __hip_bfloat16* Abf    = (__hip_bfloat16*)p;  p += (size_t)total * 512 * 2;
    __hip_bfloat16* qk     = (__hip_bfloat16*)p;  p += (size_t)total * 1024 * 2;
    __hip_bfloat16* vT     = (__hip_bfloat16*)p;  p += (size_t)64 * 8 * 64 * 256 * 2;

    int nA = total * 512, nWi = 1536 * 512, nWo = 512 * 512;

    k_detect<<<1, 256, 0, stream>>>((const unsigned short*)att_in, flag);
    long long zblocks = ((long long)out_size * 4 / 16 + 255) / 256;
    k_zero<<<(int)zblocks, 256, 0, stream>>>((char*)d_out, out_size, flag);
    k_offsets<<<1, 64, 0, stream>>>(agents, offs);
    k_cast<<<(nA / 4 + 255) / 256, 256, 0, stream>>>(att_in, (unsigned short*)Abf, nA, flag);
    k_cast<<<(nWi / 4 + 255) / 256, 256, 0, stream>>>(w_in, (unsigned short*)WinBf, nWi, flag);
    k_cast<<<(nWo / 4 + 255) / 256, 256, 0, stream>>>(w_out, (unsigned short*)WoutBf, nWo, flag);
    k_castb<<<(1536 + 255) / 256, 256, 0, stream>>>(b_in, bfi, 1536, flag);
    k_castb<<<(512 + 255) / 256, 256, 0, stream>>>(b_out, bfo, 512, flag);

    int MT = (total + 127) / 128;
    k_qkv<<<dim3(12, MT), 256, 0, stream>>>(Abf, WinBf, bfi, offs, qk, vT, total);
    k_attn<<<512, 256, 0, stream>>>(qk, vT, agents, offs);
    k_out<<<dim3(4, MT), 256, 0, stream>>>(qk, WoutBf, bfo, offs, d_out, flag, total);
}

// Round 4
// 245.065 us; speedup vs baseline: 1.6394x; 1.0076x over previous
//
#include <hip/hip_runtime.h>
#include <hip/hip_bf16.h>

typedef __attribute__((ext_vector_type(8))) short bf16x8;
typedef __attribute__((ext_vector_type(4))) float f32x4;
typedef __attribute__((ext_vector_type(4))) int i32x4;
typedef __attribute__((ext_vector_type(4))) unsigned short u16x4;
typedef __attribute__((ext_vector_type(4))) float fl4;

#define NEGV -1e9f

__device__ __forceinline__ f32x4 mfma16(bf16x8 a, bf16x8 b, f32x4 c) {
    return __builtin_amdgcn_mfma_f32_16x16x32_bf16(a, b, c, 0, 0, 0);
}

__device__ __forceinline__ unsigned short f2b(float f) {
    unsigned u = __float_as_uint(f);
    unsigned r = (u + 0x7FFF + ((u >> 16) & 1)) >> 16;
    return (unsigned short)r;
}

// async global->LDS, 16B per lane; lds base must be wave-uniform (HW adds lane*16)
__device__ __forceinline__ void gld_lds16(const __hip_bfloat16* g, __hip_bfloat16* l) {
    __builtin_amdgcn_global_load_lds(
        (const __attribute__((address_space(1))) void*)g,
        (__attribute__((address_space(3))) void*)l,
        16, 0, 0);
}

// -------- dtype detect: flag=1 if att_in is raw float32 data ----------------
__global__ void k_detect(const unsigned short* __restrict__ src, int* __restrict__ flag) {
    __shared__ int sh[256];
    int tid = threadIdx.x;
    int h = 0;
    for (int i = tid; i < 16384; i += 256) {
        unsigned e = (src[i] >> 7) & 0xFF;
        if (e == 0xFF) h = 1;
    }
    sh[tid] = h;
    __syncthreads();
    if (tid == 0) {
        int any = 0;
        for (int i = 0; i < 256; ++i) any |= sh[i];
        flag[0] = any;
    }
}

// -------- zero d_out (size depends on output dtype) -------------------------
__global__ void k_zero(char* __restrict__ out, long long out_elems, const int* __restrict__ flag) {
    long long bytes = flag[0] ? out_elems * 4 : out_elems * 2;
    long long i = ((long long)blockIdx.x * 256 + threadIdx.x) * 16;
    if (i < bytes) *(i32x4*)(out + i) = (i32x4){0, 0, 0, 0};
}

// -------- offsets: exclusive cumsum of agents[64], offs[64]=total -----------
__global__ void k_offsets(const int* __restrict__ agents, int* __restrict__ offs) {
    __shared__ int sa[64];
    int t = threadIdx.x;
    sa[t] = agents[t];
    __syncthreads();
    int ex = 0;
    for (int i = 0; i < 64; ++i) { int v = sa[i]; if (i < t) ex += v; }
    offs[t] = ex;
    if (t == 63) offs[64] = ex + sa[63];
}

// -------- cast tensor to canonical bf16 (n % 4 == 0) ------------------------
__global__ void k_cast(const void* __restrict__ src, unsigned short* __restrict__ dst,
                       int n, const int* __restrict__ flag) {
    int i = (blockIdx.x * 256 + threadIdx.x) * 4;
    if (i >= n) return;
    u16x4 o;
    if (flag[0]) {
        fl4 v = *(const fl4*)((const float*)src + i);
        o[0] = f2b(v[0]); o[1] = f2b(v[1]); o[2] = f2b(v[2]); o[3] = f2b(v[3]);
    } else {
        o = *(const u16x4*)((const unsigned short*)src + i);
    }
    *(u16x4*)(dst + i) = o;
}

// -------- cast bias to canonical f32 ---------------------------------------
__global__ void k_castb(const void* __restrict__ src, float* __restrict__ dst,
                        int n, const int* __restrict__ flag) {
    int i = blockIdx.x * 256 + threadIdx.x;
    if (i >= n) return;
    dst[i] = flag[0] ? ((const float*)src)[i]
                     : __bfloat162float(((const __hip_bfloat16*)src)[i]);
}

// -------- m97-style 128x128x512 GEMM core (A row-major LDA, W [N][512]) -----
// acc[i][j]: m = m0 + wr*64 + i*16 + quad*4 + reg ; col = n0 + wc*64 + j*16 + c
template<int LDA>
__device__ __forceinline__ void gemm_core(
    const __hip_bfloat16* __restrict__ A,
    const __hip_bfloat16* __restrict__ W,
    int m0, int n0, int total,
    __hip_bfloat16* As, __hip_bfloat16* Ws,
    f32x4 acc[4][4], int tid)
{
    int lane = tid & 63, quad = lane >> 4, c = lane & 15;
    int wave = tid >> 6;
    int wr = wave >> 1, wc = wave & 1;

    int chunk0 = tid;          // [0,256)
    int chunk1 = 256 + tid;    // [256,512)
    int ar0 = m0 + (chunk0 >> 2); if (ar0 > total - 1) ar0 = total - 1;
    int ar1 = m0 + (chunk1 >> 2); if (ar1 > total - 1) ar1 = total - 1;
    const __hip_bfloat16* gA0 = A + (size_t)ar0 * LDA + (chunk0 & 3) * 8;
    const __hip_bfloat16* gA1 = A + (size_t)ar1 * LDA + (chunk1 & 3) * 8;
    const __hip_bfloat16* gW0 = W + (size_t)(n0 + (chunk0 >> 2)) * 512 + (chunk0 & 3) * 8;
    const __hip_bfloat16* gW1 = W + (size_t)(n0 + (chunk1 >> 2)) * 512 + (chunk1 & 3) * 8;
    __hip_bfloat16* lA0 = As + (size_t)(wave * 64) * 8;          // wave-uniform
    __hip_bfloat16* lA1 = As + (size_t)(256 + wave * 64) * 8;
    __hip_bfloat16* lW0 = Ws + (size_t)(wave * 64) * 8;
    __hip_bfloat16* lW1 = Ws + (size_t)(256 + wave * 64) * 8;

    for (int k0 = 0; k0 < 512; k0 += 32) {
        if (k0) __syncthreads();
        gld_lds16(gA0 + k0, lA0);
        gld_lds16(gA1 + k0, lA1);
        gld_lds16(gW0 + k0, lW0);
        gld_lds16(gW1 + k0, lW1);
        __syncthreads();
        bf16x8 af[4], wf[4];
#pragma unroll
        for (int t = 0; t < 4; ++t) {
            af[t] = *(const bf16x8*)(As + (size_t)(wr * 64 + t * 16 + c) * 32 + quad * 8);
            wf[t] = *(const bf16x8*)(Ws + (size_t)(wc * 64 + t * 16 + c) * 32 + quad * 8);
        }
#pragma unroll
        for (int i = 0; i < 4; ++i)
#pragma unroll
            for (int j = 0; j < 4; ++j)
                acc[i][j] = mfma16(af[i], wf[j], acc[i][j]);
    }
}

// -------- QKV projection: qk[total][1024], vT[b][h][64][256] ----------------
__global__ __launch_bounds__(256) void k_qkv(
    const __hip_bfloat16* __restrict__ A,    // [total][512]
    const __hip_bfloat16* __restrict__ W,    // [1536][512]
    const float* __restrict__ bias,          // [1536]
    const int* __restrict__ offs,            // [65]
    __hip_bfloat16* __restrict__ qk,         // [total][1024]
    __hip_bfloat16* __restrict__ vT,         // [64*8*64][256]
    int total)
{
    __shared__ __hip_bfloat16 As[128 * 32];
    __shared__ __hip_bfloat16 Ws[128 * 32];
    __shared__ int s_off[65];
    int tid = threadIdx.x;
    if (tid < 65) s_off[tid] = offs[tid];
    int n0 = blockIdx.x * 128;
    int m0 = blockIdx.y * 128;
    f32x4 z = {0.f, 0.f, 0.f, 0.f};
    f32x4 acc[4][4] = {{z,z,z,z},{z,z,z,z},{z,z,z,z},{z,z,z,z}};
    gemm_core<512>(A, W, m0, n0, total, As, Ws, acc, tid);

    int lane = tid & 63, quad = lane >> 4, c = lane & 15;
    int wave = tid >> 6, wr = wave >> 1, wc = wave & 1;
    bool vregion = (n0 >= 1024);
    float bv[4];
#pragma unroll
    for (int j = 0; j < 4; ++j) bv[j] = bias[n0 + wc * 64 + j * 16 + c];
#pragma unroll
    for (int i = 0; i < 4; ++i) {
#pragma unroll
        for (int r = 0; r < 4; ++r) {
            int m = m0 + wr * 64 + i * 16 + quad * 4 + r;
            if (m >= total) continue;
            if (!vregion) {
                size_t row = (size_t)m * 1024;
#pragma unroll
                for (int j = 0; j < 4; ++j) {
                    int col = n0 + wc * 64 + j * 16 + c;
                    qk[row + col] = __float2bfloat16(acc[i][j][r] + bv[j]);
                }
            } else {
                int lo = 0, hi = 63;
                while (lo < hi) {
                    int mid = (lo + hi + 1) >> 1;
                    if (s_off[mid] <= m) lo = mid; else hi = mid - 1;
                }
                int vs = m - s_off[lo];
#pragma unroll
                for (int j = 0; j < 4; ++j) {
                    int vc = n0 - 1024 + wc * 64 + j * 16 + c;
                    vT[((size_t)(lo * 8 + (vc >> 6)) * 64 + (vc & 63)) * 256 + vs] =
                        __float2bfloat16(acc[i][j][r] + bv[j]);
                }
            }
        }
    }
}

// -------- attention: block = (b, h, q-tile-group); waves = q-tiles ----------
__global__ __launch_bounds__(256) void k_attn(
    __hip_bfloat16* __restrict__ qk,         // [total][1024]; cols 0..511 become ctx
    const __hip_bfloat16* __restrict__ vT,   // [64*8*64][256]
    const int* __restrict__ agents,
    const int* __restrict__ offs)
{
    __shared__ __hip_bfloat16 P[4][16][264];
    __shared__ float invs[4][16];
    int bh = blockIdx.x;
    int ig = blockIdx.y;
    int b = bh >> 3, h = bh & 7;
    int n = agents[b];
    int qtiles = (n + 15) >> 4;              // 8..16
    if (ig * 4 >= qtiles) return;            // whole block idle: exit pre-barrier
    int off = offs[b];
    int ktiles = qtiles;
    int kt_pad = (ktiles + 1) & ~1;          // P zero-filled up to even tile
    int stmax = (ktiles + 1) >> 1;           // PV loop bound (32 keys per st)
    int tid = threadIdx.x;
    int wave = tid >> 6, lane = tid & 63, quad = lane >> 4, c = lane & 15;
    const __hip_bfloat16* vbase = vT + (size_t)bh * 64 * 256;

    int qt = ig * 4 + wave;
    bool active = qt < qtiles;
    int q0 = qt * 16;

    if (active) {
        int qr = q0 + c; if (qr > n - 1) qr = n - 1;
        const __hip_bfloat16* qp = qk + (size_t)(off + qr) * 1024 + h * 64 + quad * 8;
        bf16x8 aq0 = *(const bf16x8*)qp;
        bf16x8 aq1 = *(const bf16x8*)(qp + 32);
        f32x4 S[16];
#pragma unroll
        for (int kt = 0; kt < 16; ++kt) {
            if (kt < ktiles) {
                int kr = kt * 16 + c; if (kr > n - 1) kr = n - 1;
                const __hip_bfloat16* kp = qk + (size_t)(off + kr) * 1024 + 512 + h * 64 + quad * 8;
                f32x4 zz = {0.f, 0.f, 0.f, 0.f};
                zz = mfma16(aq0, *(const bf16x8*)kp, zz);
                zz = mfma16(aq1, *(const bf16x8*)(kp + 32), zz);
                S[kt] = zz;
            }
        }
        float mr[4] = {-1e30f, -1e30f, -1e30f, -1e30f};
#pragma unroll
        for (int kt = 0; kt < 16; ++kt) {
            if (kt < ktiles) {
                bool bad = (kt * 16 + c) >= n;
#pragma unroll
                for (int r = 0; r < 4; ++r) {
                    float s = bad ? NEGV : S[kt][r];
                    S[kt][r] = s;
                    mr[r] = fmaxf(mr[r], s);
                }
            }
        }
#pragma unroll
        for (int r = 0; r < 4; ++r) {
            float v = mr[r];
            v = fmaxf(v, __shfl_xor(v, 1));
            v = fmaxf(v, __shfl_xor(v, 2));
            v = fmaxf(v, __shfl_xor(v, 4));
            v = fmaxf(v, __shfl_xor(v, 8));
            mr[r] = v;
        }
        float sm[4] = {0.f, 0.f, 0.f, 0.f};
#pragma unroll
        for (int kt = 0; kt < 16; ++kt) {
            if (kt < ktiles) {
#pragma unroll
                for (int r = 0; r < 4; ++r) {
                    float p = __expf((S[kt][r] - mr[r]) * 0.125f);
                    sm[r] += p;
                    P[wave][quad * 4 + r][kt * 16 + c] = __float2bfloat16(p);
                }
            } else if (kt < kt_pad) {
#pragma unroll
                for (int r = 0; r < 4; ++r)
                    P[wave][quad * 4 + r][kt * 16 + c] = __float2bfloat16(0.f);
            }
        }
#pragma unroll
        for (int r = 0; r < 4; ++r) {
            float v = sm[r];
            v += __shfl_xor(v, 1);
            v += __shfl_xor(v, 2);
            v += __shfl_xor(v, 4);
            v += __shfl_xor(v, 8);
            if (c == 0) invs[wave][quad * 4 + r] = 1.0f / v;
        }
    }
    __syncthreads();
    if (active) {
        f32x4 z = {0.f, 0.f, 0.f, 0.f};
        f32x4 O[4] = {z, z, z, z};
#pragma unroll
        for (int st = 0; st < 8; ++st) {
            if (st < stmax) {
                bf16x8 ap = *(const bf16x8*)&P[wave][c][st * 32 + quad * 8];
#pragma unroll
                for (int dt = 0; dt < 4; ++dt) {
                    const __hip_bfloat16* vp = vbase + (size_t)(c + 16 * dt) * 256 + st * 32 + quad * 8;
                    O[dt] = mfma16(ap, *(const bf16x8*)vp, O[dt]);
                }
            }
        }
#pragma unroll
        for (int r = 0; r < 4; ++r) {
            int q = quad * 4 + r;
            if (q0 + q < n) {
                float iv = invs[wave][q];
                size_t row = (size_t)(off + q0 + q) * 1024 + h * 64;
#pragma unroll
                for (int dt = 0; dt < 4; ++dt)
                    qk[row + 16 * dt + c] = __float2bfloat16(O[dt][r] * iv);
            }
        }
    }
}

// -------- output projection into padded, zeroed d_out -----------------------
__global__ __launch_bounds__(256) void k_out(
    const __hip_bfloat16* __restrict__ A,    // ctx in qk buffer, stride 1024
    const __hip_bfloat16* __restrict__ W,    // [512][512]
    const float* __restrict__ bias,          // [512]
    const int* __restrict__ offs,            // [65]
    void* __restrict__ out,                  // [64][254][512] f32 or bf16
    const int* __restrict__ flag,
    int total)
{
    __shared__ __hip_bfloat16 As[128 * 32];
    __shared__ __hip_bfloat16 Ws[128 * 32];
    __shared__ int s_off[65];
    int tid = threadIdx.x;
    if (tid < 65) s_off[tid] = offs[tid];
    int n0 = blockIdx.x * 128;
    int m0 = blockIdx.y * 128;
    f32x4 z = {0.f, 0.f, 0.f, 0.f};
    f32x4 acc[4][4] = {{z,z,z,z},{z,z,z,z},{z,z,z,z},{z,z,z,z}};
    gemm_core<1024>(A, W, m0, n0, total, As, Ws, acc, tid);

    int f32m = flag[0];
    int lane = tid & 63, quad = lane >> 4, c = lane & 15;
    int wave = tid >> 6, wr = wave >> 1, wc = wave & 1;
    float bv[4];
#pragma unroll
    for (int j = 0; j < 4; ++j) bv[j] = bias[n0 + wc * 64 + j * 16 + c];
#pragma unroll
    for (int i = 0; i < 4; ++i) {
#pragma unroll
        for (int r = 0; r < 4; ++r) {
            int m = m0 + wr * 64 + i * 16 + quad * 4 + r;
            if (m >= total) continue;
            int lo = 0, hi = 63;
            while (lo < hi) {
                int mid = (lo + hi + 1) >> 1;
                if (s_off[mid] <= m) lo = mid; else hi = mid - 1;
            }
            int os_ = m - s_off[lo];
            size_t rowb = ((size_t)(lo * 254 + os_)) * 512;
#pragma unroll
            for (int j = 0; j < 4; ++j) {
                int col = n0 + wc * 64 + j * 16 + c;
                float v = acc[i][j][r] + bv[j];
                if (f32m) ((float*)out)[rowb + col] = v;
                else      ((__hip_bfloat16*)out)[rowb + col] = __float2bfloat16(v);
            }
        }
    }
}

extern "C" void kernel_launch(void* const* d_in, const int* in_sizes, int n_in,
                              void* d_out, int out_size, void* d_ws, size_t ws_size,
                              hipStream_t stream) {
    const void* att_in = d_in[0];
    const void* w_in   = d_in[1];
    const void* b_in   = d_in[2];
    const void* w_out  = d_in[3];
    const void* b_out  = d_in[4];
    const int* agents  = (const int*)d_in[5];
    int total = in_sizes[0] / 512;

    char* p = (char*)d_ws;
    int* flag  = (int*)p;                 p += 256;
    int* offs  = (int*)p;                 p += 512;
    float* bfi = (float*)p;               p += 1536 * 4;
    float* bfo = (float*)p;               p += 512 * 4;
    __hip_bfloat16* WinBf  = (__hip_bfloat16*)p;  p += (size_t)1536 * 512 * 2;
    __hip_bfloat16* WoutBf = (__hip_bfloat16*)p;  p += (size_t)512 * 512 * 2;
    __hip_bfloat16* Abf    = (__hip_bfloat16*)p;  p += (size_t)total * 512 * 2;
    __hip_bfloat16* qk     = (__hip_bfloat16*)p;  p += (size_t)total * 1024 * 2;
    __hip_bfloat16* vT     = (__hip_bfloat16*)p;  p += (size_t)64 * 8 * 64 * 256 * 2;

    int nA = total * 512, nWi = 1536 * 512, nWo = 512 * 512;

    k_detect<<<1, 256, 0, stream>>>((const unsigned short*)att_in, flag);
    long long zblocks = ((long long)out_size * 4 / 16 + 255) / 256;
    k_zero<<<(int)zblocks, 256, 0, stream>>>((char*)d_out, out_size, flag);
    k_offsets<<<1, 64, 0, stream>>>(agents, offs);
    k_cast<<<(nA / 4 + 255) / 256, 256, 0, stream>>>(att_in, (unsigned short*)Abf, nA, flag);
    k_cast<<<(nWi / 4 + 255) / 256, 256, 0, stream>>>(w_in, (unsigned short*)WinBf, nWi, flag);
    k_cast<<<(nWo / 4 + 255) / 256, 256, 0, stream>>>(w_out, (unsigned short*)WoutBf, nWo, flag);
    k_castb<<<(1536 + 255) / 256, 256, 0, stream>>>(b_in, bfi, 1536, flag);
    k_castb<<<(512 + 255) / 256, 256, 0, stream>>>(b_out, bfo, 512, flag);

    int MT = (total + 127) / 128;
    k_qkv<<<dim3(12, MT), 256, 0, stream>>>(Abf, WinBf, bfi, offs, qk, vT, total);
    k_attn<<<dim3(512, 4), 256, 0, stream>>>(qk, vT, agents, offs);
    k_out<<<dim3(4, MT), 256, 0, stream>>>(qk, WoutBf, bfo, offs, d_out, flag, total);
}